// Round 3
// baseline (1478.288 us; speedup 1.0000x reference)
//
#include <hip/hip_runtime.h>
#include <hip/hip_bf16.h>

typedef __hip_bfloat16 bf16;

constexpr int B  = 64, T = 120, N = 24, M = 3, D = 32;
constexpr int NH = 2, FD = 16, FF = 64, L = 3;
constexpr float SCALE = 0.25f;   // 1/sqrt(FD)
constexpr int ST = 33;           // padded LDS stride for D=32 rows

__device__ __forceinline__ float b2f(bf16 x) { return __bfloat162float(x); }

// ---------------------------------------------------------------------------
// Compose two chained per-unit linears: y = (x@W1 + b1)@W2 + b2
//   => Wc = W1@W2, bc = b1@W2 + b2.  One block per unit (node or timestep).
// ---------------------------------------------------------------------------
__global__ __launch_bounds__(256) void compose_kernel(
    const float* __restrict__ W1, const float* __restrict__ b1,
    const float* __restrict__ W2, const float* __restrict__ b2,
    float* __restrict__ Wc, float* __restrict__ bc) {
  int n = blockIdx.x;
  const float* w1 = W1 + n * D * D;
  const float* w2 = W2 + n * D * D;
  __shared__ float s1[D * D], s2[D * D];
  for (int i = threadIdx.x; i < D * D; i += 256) {
    s1[i] = w1[i];
    s2[i] = w2[i];
  }
  __syncthreads();
  for (int i = threadIdx.x; i < D * D; i += 256) {
    int d = i >> 5, f = i & 31;
    float acc = 0.f;
#pragma unroll
    for (int e = 0; e < D; ++e) acc += s1[d * D + e] * s2[e * D + f];
    Wc[n * D * D + i] = acc;
  }
  if (threadIdx.x < D) {
    int f = threadIdx.x;
    float acc = b2[n * D + f];
#pragma unroll
    for (int e = 0; e < D; ++e) acc += b1[n * D + e] * s2[e * D + f];
    bc[n * D + f] = acc;
  }
}

// ---------------------------------------------------------------------------
// E[b,t,n,d] = sum_m X[b,t,n*M+m]*E_W[n,m,d] + E_b[n,d] + pe[t,d]   (bf16 out)
// ---------------------------------------------------------------------------
__global__ __launch_bounds__(256) void embed_kernel(
    const float* __restrict__ X, const float* __restrict__ pe,
    const float* __restrict__ E_W, const float* __restrict__ E_b,
    bf16* __restrict__ E) {
  int idx = blockIdx.x * 256 + threadIdx.x;
  if (idx >= B * T * N * D) return;
  int d = idx & 31;
  int n = (idx >> 5) % N;
  int bt = idx / (D * N);
  int t = bt % T;
  const float* x = X + bt * (N * M) + n * M;
  float acc = E_b[n * D + d] + pe[t * D + d];
#pragma unroll
  for (int m = 0; m < M; ++m) acc += x[m] * E_W[(n * M + m) * D + d];
  E[idx] = __float2bfloat16(acc);
}

// ---------------------------------------------------------------------------
// Temporal attention, fused per (b, n).  LDS: 4 arrays, 63.4 KB (< 64 KB).
// Weight columns live in registers (e = tid&31 is iteration-invariant).
// Q is staged in Os and overwritten in place by softmax (self-only RW).
// ---------------------------------------------------------------------------
__global__ __launch_bounds__(256) void temporal_kernel(
    const bf16* __restrict__ E, const float* __restrict__ WtC,
    const float* __restrict__ btC, const float* __restrict__ tm_Wo,
    const float* __restrict__ tm_bo, const float* __restrict__ ln_g,
    const float* __restrict__ ln_b, bf16* __restrict__ Tn) {
  int b = blockIdx.x / N;
  int n = blockIdx.x % N;
  __shared__ float Es[T * ST], Ks[T * ST], Vs[T * ST], Os[T * ST];
  int tid = threadIdx.x;
  int e = tid & 31;

  for (int i = tid; i < T * D; i += 256) {
    int t = i >> 5, d = i & 31;
    Es[t * ST + d] = b2f(E[((size_t)(b * T + t) * N + n) * D + d]);
  }
  __syncthreads();

  // --- Q (into Os) and K projections ---
  {
    const float* wqg = WtC + (0 * N + n) * D * D;
    const float* wkg = WtC + (1 * N + n) * D * D;
    float wq[D], wk[D];
#pragma unroll
    for (int d = 0; d < D; ++d) { wq[d] = wqg[d * D + e]; wk[d] = wkg[d * D + e]; }
    float bqv = btC[(0 * N + n) * D + e];
    float bkv = btC[(1 * N + n) * D + e];
#pragma unroll
    for (int k = 0; k < T * D / 256; ++k) {
      int t = (tid + k * 256) >> 5;
      float aq = bqv, ak = bkv;
#pragma unroll
      for (int d = 0; d < D; ++d) {
        float x = Es[t * ST + d];
        aq += x * wq[d];
        ak += x * wk[d];
      }
      Os[t * ST + e] = aq;
      Ks[t * ST + e] = ak;
    }
  }
  // --- V projection ---
  {
    const float* wvg = WtC + (2 * N + n) * D * D;
    float wv[D];
#pragma unroll
    for (int d = 0; d < D; ++d) wv[d] = wvg[d * D + e];
    float bvv = btC[(2 * N + n) * D + e];
#pragma unroll
    for (int k = 0; k < T * D / 256; ++k) {
      int t = (tid + k * 256) >> 5;
      float av = bvv;
#pragma unroll
      for (int d = 0; d < D; ++d) av += Es[t * ST + d] * wv[d];
      Vs[t * ST + e] = av;
    }
  }
  __syncthreads();

  // --- causal online softmax, one thread per (t, h) ---
  if (tid < T * NH) {
    int t = tid >> 1, h = tid & 1;
    int ho = h * FD;
    float q[FD];
#pragma unroll
    for (int f = 0; f < FD; ++f) q[f] = Os[t * ST + ho + f];
    float m = -1e30f, l = 0.f;
    float acc[FD];
#pragma unroll
    for (int f = 0; f < FD; ++f) acc[f] = 0.f;
    for (int k = 0; k <= t; ++k) {
      float s = 0.f;
#pragma unroll
      for (int f = 0; f < FD; ++f) s += q[f] * Ks[k * ST + ho + f];
      s *= SCALE;
      float nm = fmaxf(m, s);
      float cf = __expf(m - nm);
      float p  = __expf(s - nm);
      l = l * cf + p;
#pragma unroll
      for (int f = 0; f < FD; ++f) acc[f] = acc[f] * cf + p * Vs[k * ST + ho + f];
      m = nm;
    }
    float rl = 1.f / l;
#pragma unroll
    for (int f = 0; f < FD; ++f) Os[t * ST + ho + f] = acc[f] * rl;
  }
  __syncthreads();

  // --- output projection + residual into Ks ---
  {
    const float* wog = tm_Wo + n * D * D;
    float wo[D];
#pragma unroll
    for (int d = 0; d < D; ++d) wo[d] = wog[d * D + e];
    float bov = tm_bo[n * D + e];
#pragma unroll
    for (int k = 0; k < T * D / 256; ++k) {
      int t = (tid + k * 256) >> 5;
      float a = bov;
#pragma unroll
      for (int d = 0; d < D; ++d) a += Os[t * ST + d] * wo[d];
      Ks[t * ST + e] = a + Es[t * ST + e];
    }
  }
  __syncthreads();

  // --- LayerNorm, one thread per row ---
  if (tid < T) {
    int t = tid;
    float mu = 0.f;
#pragma unroll
    for (int d = 0; d < D; ++d) mu += Ks[t * ST + d];
    mu *= (1.f / D);
    float var = 0.f;
#pragma unroll
    for (int d = 0; d < D; ++d) { float c = Ks[t * ST + d] - mu; var += c * c; }
    var *= (1.f / D);
    float r = rsqrtf(var + 1e-5f);
#pragma unroll
    for (int d = 0; d < D; ++d)
      Tn[((size_t)(b * T + t) * N + n) * D + d] =
          __float2bfloat16((Ks[t * ST + d] - mu) * r * ln_g[d] + ln_b[d]);
  }
}

// ---------------------------------------------------------------------------
// Spatial attention, fused per (b, t).  Same structure, N=24 rows, 12.7 KB LDS.
// ---------------------------------------------------------------------------
__global__ __launch_bounds__(64) void spatial_kernel(
    const bf16* __restrict__ E, const float* __restrict__ WsC,
    const float* __restrict__ bsC, const float* __restrict__ sm_Wo,
    const float* __restrict__ sm_bo, const float* __restrict__ ln_g,
    const float* __restrict__ ln_b, bf16* __restrict__ Sn) {
  int b = blockIdx.x / T;
  int t = blockIdx.x % T;
  __shared__ float Es[N * ST], Ks[N * ST], Vs[N * ST], Os[N * ST];
  int tid = threadIdx.x;
  int e = tid & 31;

  for (int i = tid; i < N * D; i += 64) {
    int nn = i >> 5, d = i & 31;
    Es[nn * ST + d] = b2f(E[((size_t)(b * T + t) * N + nn) * D + d]);
  }
  __syncthreads();

  {
    const float* wqg = WsC + (0 * T + t) * D * D;
    const float* wkg = WsC + (1 * T + t) * D * D;
    float wq[D], wk[D];
#pragma unroll
    for (int d = 0; d < D; ++d) { wq[d] = wqg[d * D + e]; wk[d] = wkg[d * D + e]; }
    float bqv = bsC[(0 * T + t) * D + e];
    float bkv = bsC[(1 * T + t) * D + e];
#pragma unroll
    for (int k = 0; k < N * D / 64; ++k) {
      int nn = (tid + k * 64) >> 5;
      float aq = bqv, ak = bkv;
#pragma unroll
      for (int d = 0; d < D; ++d) {
        float x = Es[nn * ST + d];
        aq += x * wq[d];
        ak += x * wk[d];
      }
      Os[nn * ST + e] = aq;
      Ks[nn * ST + e] = ak;
    }
  }
  {
    const float* wvg = WsC + (2 * T + t) * D * D;
    float wv[D];
#pragma unroll
    for (int d = 0; d < D; ++d) wv[d] = wvg[d * D + e];
    float bvv = bsC[(2 * T + t) * D + e];
#pragma unroll
    for (int k = 0; k < N * D / 64; ++k) {
      int nn = (tid + k * 64) >> 5;
      float av = bvv;
#pragma unroll
      for (int d = 0; d < D; ++d) av += Es[nn * ST + d] * wv[d];
      Vs[nn * ST + e] = av;
    }
  }
  __syncthreads();

  if (tid < N * NH) {
    int nn = tid >> 1, h = tid & 1;
    int ho = h * FD;
    float q[FD];
#pragma unroll
    for (int f = 0; f < FD; ++f) q[f] = Os[nn * ST + ho + f];
    float sc[N];
    float m = -1e30f;
#pragma unroll
    for (int k = 0; k < N; ++k) {
      float s = 0.f;
#pragma unroll
      for (int f = 0; f < FD; ++f) s += q[f] * Ks[k * ST + ho + f];
      s *= SCALE;
      sc[k] = s;
      m = fmaxf(m, s);
    }
    float l = 0.f;
#pragma unroll
    for (int k = 0; k < N; ++k) { sc[k] = __expf(sc[k] - m); l += sc[k]; }
    float rl = 1.f / l;
#pragma unroll
    for (int f = 0; f < FD; ++f) {
      float a = 0.f;
#pragma unroll
      for (int k = 0; k < N; ++k) a += sc[k] * Vs[k * ST + ho + f];
      Os[nn * ST + ho + f] = a * rl;
    }
  }
  __syncthreads();

  {
    const float* wog = sm_Wo + t * D * D;
    float wo[D];
#pragma unroll
    for (int d = 0; d < D; ++d) wo[d] = wog[d * D + e];
    float bov = sm_bo[t * D + e];
#pragma unroll
    for (int k = 0; k < N * D / 64; ++k) {
      int nn = (tid + k * 64) >> 5;
      float a = bov;
#pragma unroll
      for (int d = 0; d < D; ++d) a += Os[nn * ST + d] * wo[d];
      Ks[nn * ST + e] = a + Es[nn * ST + e];
    }
  }
  __syncthreads();

  if (tid < N) {
    int nn = tid;
    float mu = 0.f;
#pragma unroll
    for (int d = 0; d < D; ++d) mu += Ks[nn * ST + d];
    mu *= (1.f / D);
    float var = 0.f;
#pragma unroll
    for (int d = 0; d < D; ++d) { float c = Ks[nn * ST + d] - mu; var += c * c; }
    var *= (1.f / D);
    float r = rsqrtf(var + 1e-5f);
#pragma unroll
    for (int d = 0; d < D; ++d)
      Sn[((size_t)(b * T + t) * N + nn) * D + d] =
          __float2bfloat16((Ks[nn * ST + d] - mu) * r * ln_g[d] + ln_b[d]);
  }
}

// ---------------------------------------------------------------------------
// ts = Tn + Sn; ff = relu(ts@W1+b1)@W2+b2; E = LN(ff + ts).  Row per thread.
// ---------------------------------------------------------------------------
__global__ __launch_bounds__(256) void ff_kernel(
    const bf16* __restrict__ Tn, const bf16* __restrict__ Sn,
    const float* __restrict__ W1, const float* __restrict__ b1,
    const float* __restrict__ W2, const float* __restrict__ b2,
    const float* __restrict__ ln_g, const float* __restrict__ ln_b,
    bf16* __restrict__ E) {
  __shared__ float w1[D * FF], w2[FF * D], bb1[FF], bb2[D], g[D], bbn[D];
  int tid = threadIdx.x;
  for (int i = tid; i < D * FF; i += 256) {
    w1[i] = W1[i];
    w2[i] = W2[i];
  }
  if (tid < FF) bb1[tid] = b1[tid];
  if (tid < D) {
    bb2[tid] = b2[tid];
    g[tid]   = ln_g[tid];
    bbn[tid] = ln_b[tid];
  }
  __syncthreads();
  int row = blockIdx.x * 256 + tid;
  if (row >= B * T * N) return;
  float ts[D];
#pragma unroll
  for (int d = 0; d < D; ++d)
    ts[d] = b2f(Tn[(size_t)row * D + d]) + b2f(Sn[(size_t)row * D + d]);
  float h[FF];
#pragma unroll
  for (int j = 0; j < FF; ++j) {
    float a = bb1[j];
#pragma unroll
    for (int d = 0; d < D; ++d) a += ts[d] * w1[d * FF + j];
    h[j] = fmaxf(a, 0.f);
  }
  float x[D];
  float mu = 0.f;
#pragma unroll
  for (int e = 0; e < D; ++e) {
    float a = bb2[e];
#pragma unroll
    for (int j = 0; j < FF; ++j) a += h[j] * w2[j * D + e];
    a += ts[e];
    x[e] = a;
    mu += a;
  }
  mu *= (1.f / D);
  float var = 0.f;
#pragma unroll
  for (int e = 0; e < D; ++e) { float c = x[e] - mu; var += c * c; }
  var *= (1.f / D);
  float r = rsqrtf(var + 1e-5f);
#pragma unroll
  for (int e = 0; e < D; ++e)
    E[(size_t)row * D + e] = __float2bfloat16((x[e] - mu) * r * g[e] + bbn[e]);
}

// ---------------------------------------------------------------------------
// out[b,t,n,m] = E[b,t,n,:]@op_W[n,:,m] + op_b[n,m] + X[b,t,n*M+m]  (f32 out)
// ---------------------------------------------------------------------------
__global__ __launch_bounds__(256) void out_kernel(
    const bf16* __restrict__ E, const float* __restrict__ op_W,
    const float* __restrict__ op_b, const float* __restrict__ X,
    float* __restrict__ out) {
  int idx = blockIdx.x * 256 + threadIdx.x;
  if (idx >= B * T * N * M) return;
  int m  = idx % M;
  int n  = (idx / M) % N;
  int bt = idx / (M * N);
  float acc = op_b[n * M + m];
  const bf16* e = E + ((size_t)bt * N + n) * D;
#pragma unroll
  for (int d = 0; d < D; ++d) acc += b2f(e[d]) * op_W[(n * D + d) * M + m];
  acc += X[idx];
  out[idx] = acc;
}

// ---------------------------------------------------------------------------
extern "C" void kernel_launch(void* const* d_in, const int* in_sizes, int n_in,
                              void* d_out, int out_size, void* d_ws, size_t ws_size,
                              hipStream_t stream) {
  const float* X     = (const float*)d_in[0];
  const float* pe    = (const float*)d_in[1];
  const float* E_W   = (const float*)d_in[2];
  const float* E_b   = (const float*)d_in[3];
  const float* tq_W  = (const float*)d_in[4];
  const float* tq_b  = (const float*)d_in[5];
  const float* tk_W  = (const float*)d_in[6];
  const float* tk_b  = (const float*)d_in[7];
  const float* tv_W  = (const float*)d_in[8];
  const float* tv_b  = (const float*)d_in[9];
  const float* tm_Wq = (const float*)d_in[10];
  const float* tm_bq = (const float*)d_in[11];
  const float* tm_Wk = (const float*)d_in[12];
  const float* tm_bk = (const float*)d_in[13];
  const float* tm_Wv = (const float*)d_in[14];
  const float* tm_bv = (const float*)d_in[15];
  const float* tm_Wo = (const float*)d_in[16];
  const float* tm_bo = (const float*)d_in[17];
  const float* sq_W  = (const float*)d_in[18];
  const float* sq_b  = (const float*)d_in[19];
  const float* sk_W  = (const float*)d_in[20];
  const float* sk_b  = (const float*)d_in[21];
  const float* sv_W  = (const float*)d_in[22];
  const float* sv_b  = (const float*)d_in[23];
  const float* sm_Wq = (const float*)d_in[24];
  const float* sm_bq = (const float*)d_in[25];
  const float* sm_Wk = (const float*)d_in[26];
  const float* sm_bk = (const float*)d_in[27];
  const float* sm_Wv = (const float*)d_in[28];
  const float* sm_bv = (const float*)d_in[29];
  const float* sm_Wo = (const float*)d_in[30];
  const float* sm_bo = (const float*)d_in[31];
  const float* ff1_W = (const float*)d_in[32];
  const float* ff1_b = (const float*)d_in[33];
  const float* ff2_W = (const float*)d_in[34];
  const float* ff2_b = (const float*)d_in[35];
  const float* ln_g  = (const float*)d_in[36];
  const float* ln_b  = (const float*)d_in[37];
  const float* op_W  = (const float*)d_in[38];
  const float* op_b  = (const float*)d_in[39];
  float* out = (float*)d_out;

  // workspace: f32 composed weights first, then bf16 activations (~37.2 MB)
  float* WtC = (float*)d_ws;                         // 3*N*D*D = 73728 f
  float* btC = WtC + 3 * N * D * D;                  // 3*N*D   = 2304 f
  float* WsC = btC + 3 * N * D;                      // 3*T*D*D = 368640 f
  float* bsC = WsC + 3 * T * D * D;                  // 3*T*D   = 11520 f
  size_t act = (size_t)B * T * N * D;
  bf16* Ebuf = (bf16*)(bsC + 3 * T * D);
  bf16* Tn   = Ebuf + act;
  bf16* Sn   = Tn + act;

  compose_kernel<<<N, 256, 0, stream>>>(tq_W, tq_b, tm_Wq, tm_bq, WtC + 0 * N * D * D, btC + 0 * N * D);
  compose_kernel<<<N, 256, 0, stream>>>(tk_W, tk_b, tm_Wk, tm_bk, WtC + 1 * N * D * D, btC + 1 * N * D);
  compose_kernel<<<N, 256, 0, stream>>>(tv_W, tv_b, tm_Wv, tm_bv, WtC + 2 * N * D * D, btC + 2 * N * D);
  compose_kernel<<<T, 256, 0, stream>>>(sq_W, sq_b, sm_Wq, sm_bq, WsC + 0 * T * D * D, bsC + 0 * T * D);
  compose_kernel<<<T, 256, 0, stream>>>(sk_W, sk_b, sm_Wk, sm_bk, WsC + 1 * T * D * D, bsC + 1 * T * D);
  compose_kernel<<<T, 256, 0, stream>>>(sv_W, sv_b, sm_Wv, sm_bv, WsC + 2 * T * D * D, bsC + 2 * T * D);

  embed_kernel<<<(B * T * N * D) / 256, 256, 0, stream>>>(X, pe, E_W, E_b, Ebuf);

  for (int l = 0; l < L; ++l) {
    temporal_kernel<<<B * N, 256, 0, stream>>>(Ebuf, WtC, btC, tm_Wo, tm_bo, ln_g, ln_b, Tn);
    spatial_kernel<<<B * T, 64, 0, stream>>>(Ebuf, WsC, bsC, sm_Wo, sm_bo, ln_g, ln_b, Sn);
    ff_kernel<<<(B * T * N) / 256, 256, 0, stream>>>(Tn, Sn, ff1_W, ff1_b, ff2_W, ff2_b, ln_g, ln_b, Ebuf);
  }

  out_kernel<<<(B * T * N * M) / 256, 256, 0, stream>>>(Ebuf, op_W, op_b, X, out);
}